// Round 13
// baseline (67.493 us; speedup 1.0000x reference)
//
#include <hip/hip_runtime.h>
#include <math.h>

#define NJ 4         // odd powers x^1..x^7
#define DEG 7
#define X0f 1.1f     // poly valid on [-1.1,1.1]; typical |s*g| ~ 0.4
#define NB 8         // batch rows per block
#define NT 1024      // threads per block (16 waves, 4/SIMD)

struct Poly { float c[NJ]; };

typedef float v4f __attribute__((ext_vector_type(4)));

// ---------------- K0: repack weights ----------------
__global__ __launch_bounds__(256) void k_repack(
    const float* __restrict__ Wc, const float* __restrict__ W1,
    const float* __restrict__ eW0, const float* __restrict__ eW1, const float* __restrict__ eW2,
    float* __restrict__ WcT, float* __restrict__ W1T,
    float* __restrict__ Wt0, float* __restrict__ Wt1, float* __restrict__ Wt2) {
    int tid = blockIdx.x * 256 + threadIdx.x;
    int stride = gridDim.x * 256;
    for (int idx = tid; idx < 3 * 464 * 32; idx += stride) {
        int i = idx / (464 * 32); int rem = idx - i * 464 * 32;
        int m = rem >> 5, h = rem & 31;
        float v = 0.f;
        if (m < 456) {
            int seg = m / 152, e = m - seg * 152;
            if (e < 150) v = Wc[((size_t)i * 32 + h) * 450 + seg * 150 + e];
        }
        WcT[idx] = v;
    }
    for (int idx = tid; idx < 456 * 128; idx += stride) {
        int m = idx >> 7, k = idx & 127;
        int seg = m / 152, e = m - seg * 152;
        W1T[idx] = (e < 150) ? W1[k * 450 + seg * 150 + e] : 0.f;
    }
    for (int idx = tid; idx < 304 * 152; idx += stride) {
        int d = idx / 152, e = idx - d * 152;
        Wt0[idx] = (d < 300 && e < 150) ? eW0[e * 300 + d] : 0.f;
    }
    for (int idx = tid; idx < 76 * 152; idx += stride) {
        int d = idx / 152, e = idx - d * 152;
        Wt1[idx] = (d < 74 && e < 150) ? eW1[e * 74 + d] : 0.f;
    }
    for (int idx = tid; idx < 36 * 152; idx += stride) {
        int d = idx / 152, e = idx - d * 152;
        Wt2[idx] = (d < 35 && e < 150) ? eW2[e * 35 + d] : 0.f;
    }
}

// ---------------- K1: fully fused enc -> attn -> cls. grid 256, block 1024 ----------------
__global__ __launch_bounds__(NT, 1) void k_fused(
    const float* __restrict__ x0, const float* __restrict__ x1, const float* __restrict__ x2,
    const float* __restrict__ eb0, const float* __restrict__ eb1, const float* __restrict__ eb2,
    const float* __restrict__ Wt0, const float* __restrict__ Wt1, const float* __restrict__ Wt2,
    const float* __restrict__ WcT,
    const float* __restrict__ affw, const float* __restrict__ Ww, const float* __restrict__ Wh,
    const float* __restrict__ W1T, const float* __restrict__ cb1,
    const float* __restrict__ cW2, const float* __restrict__ cb2,
    float* __restrict__ out, Poly pc) {
#pragma clang fp contract(fast)
    // R: union region. P0/P1: xs[8][428] (3424f). P2: Mp[48][8][4] v4f (6144f).
    // P3: clsP[4][8][32] v4f (4096f).
    __shared__ __align__(16) float R[6144];
    __shared__ __align__(16) float featf[NB * 468]; // enc outputs; rows reused as hs
    __shared__ __align__(16) float fof[NB * 468];   // attn outputs (cls input)
    __shared__ __align__(16) float wWs[96], wHs[96];
    __shared__ float mxs[48];                        // per-half row-max partials

    int tid = threadIdx.x;
    int b0 = blockIdx.x * NB;
    float* xs = R;            // stride 428 per b
    v4f* Mp4 = (v4f*)R;
    v4f* clsP4 = (v4f*)R;

    // ---- P0: stage x, small weights, zero feat pads ----
    if (tid < 96) { wWs[tid] = Ww[tid]; wHs[tid] = Wh[tid]; }
    if (tid >= 96 && tid < 192) {           // zero featf pads 456..467
        int q = tid - 96; int b = q / 12, r = q - b * 12;
        featf[b * 468 + 456 + r] = 0.f;
    }
    if (tid >= 192 && tid < 240) {          // zero fof segment pads (e=150,151)
        int q = tid - 192; int b = q / 6, r = q - b * 6;
        fof[b * 468 + (r >> 1) * 152 + 150 + (r & 1)] = 0.f;
    }
    for (int idx = tid; idx < NB * 75; idx += NT) {
        int b = idx / 75, q = idx - b * 75;
        ((v4f*)(xs + b * 428))[q] = ((const v4f*)(x0 + (size_t)(b0 + b) * 300))[q];
    }
    for (int idx = tid; idx < NB * 74; idx += NT) {
        int b = idx / 74, d = idx - b * 74;
        xs[b * 428 + 304 + d] = x1[(size_t)(b0 + b) * 74 + d];
    }
    for (int idx = tid; idx < NB * 35; idx += NT) {
        int b = idx / 35, d = idx - b * 35;
        xs[b * 428 + 380 + d] = x2[(size_t)(b0 + b) * 35 + d];
    }
    __syncthreads();

    // ---- P1: encoders. 912 tasks = (m4 = t>>3, b = t&7); one task/thread ----
    if (tid < 912) {
        int b = tid & 7, m4 = tid >> 3;
        int seg = (m4 >= 76) ? 2 : (m4 >= 38) ? 1 : 0;
        int e4 = m4 - seg * 38;
        const float* eb = seg == 0 ? eb0 : seg == 1 ? eb1 : eb2;
        const v4f* Wt4 = (const v4f*)(seg == 0 ? Wt0 : seg == 1 ? Wt1 : Wt2) + e4;
        const float* xb = xs + b * 428 + (seg == 0 ? 0 : seg == 1 ? 304 : 380);
        int DP4 = seg == 0 ? 76 : seg == 1 ? 19 : 9;
        const v4f* xr = (const v4f*)xb;
        int e = e4 * 4;
        v4f acc = { (e < 150) ? eb[e] : 0.f,
                    (e + 1 < 150) ? eb[e + 1] : 0.f,
                    (e + 2 < 150) ? eb[e + 2] : 0.f,
                    (e + 3 < 150) ? eb[e + 3] : 0.f };
        for (int d4 = 0; d4 < DP4; ++d4) {
            v4f x4 = xr[d4];
            v4f w0 = Wt4[(d4 * 4 + 0) * 38];
            v4f w1 = Wt4[(d4 * 4 + 1) * 38];
            v4f w2 = Wt4[(d4 * 4 + 2) * 38];
            v4f w3 = Wt4[(d4 * 4 + 3) * 38];
            acc += x4.x * w0;
            acc += x4.y * w1;
            acc += x4.z * w2;
            acc += x4.w * w3;
        }
        ((v4f*)(featf + b * 468))[m4] = acc;
    }
    __syncthreads();

    // ---- P2a: M-phase. 48 half-units (unit = (i,b), half = 228 c); wave w does 3.
    //      lane = hq(3b) | slice(3b); shuffle-reduce slices; slice0 lanes write Mp ----
    {
        int w = tid >> 6, lane = tid & 63;
        int hq = lane & 7, slice = (lane >> 3) & 7;
        #pragma unroll
        for (int q = 0; q < 3; ++q) {
            int h = w * 3 + q;
            int u = h >> 1, ch = h & 1;
            int i = u >> 3, b = u & 7;
            float aff = affw[i];
            const v4f* Wb4 = (const v4f*)WcT + (size_t)i * 3712 + hq;
            const float* fb = featf + b * 468;
            int clo = ch * 228 + ((slice < 4) ? slice * 29 : 116 + (slice - 4) * 28);
            int cn = (slice < 4) ? 29 : 28;
            v4f acc[NJ];
            #pragma unroll
            for (int J = 0; J < NJ; ++J) acc[J] = (v4f)0.f;
            float mx = 0.f;
            #pragma unroll 4
            for (int k = 0; k < cn; ++k) {
                int c = clo + k;
                float f = fb[c];
                v4f wv = Wb4[(size_t)c * 8];
                mx = fmaxf(mx, fabsf(f));
                float g = aff * f, g2 = g * g;
                float p = g;
                acc[0] += p * wv;
                #pragma unroll
                for (int J = 1; J < NJ; ++J) { p *= g2; acc[J] += p * wv; }
            }
            // reduce across slice bits (8,16,32), fold poly coeff
            #pragma unroll
            for (int J = 0; J < NJ; ++J) {
                float cJ = pc.c[J];
                float vx = acc[J].x; vx += __shfl_xor(vx, 8); vx += __shfl_xor(vx, 16); vx += __shfl_xor(vx, 32);
                float vy = acc[J].y; vy += __shfl_xor(vy, 8); vy += __shfl_xor(vy, 16); vy += __shfl_xor(vy, 32);
                float vz = acc[J].z; vz += __shfl_xor(vz, 8); vz += __shfl_xor(vz, 16); vz += __shfl_xor(vz, 32);
                float vw = acc[J].w; vw += __shfl_xor(vw, 8); vw += __shfl_xor(vw, 16); vw += __shfl_xor(vw, 32);
                acc[J] = (v4f){ vx * cJ, vy * cJ, vz * cJ, vw * cJ };
            }
            mx = fmaxf(mx, __shfl_xor(mx, 8));
            mx = fmaxf(mx, __shfl_xor(mx, 16));
            mx = fmaxf(mx, __shfl_xor(mx, 32));
            if (slice == 0) {
                #pragma unroll
                for (int J = 0; J < NJ; ++J) Mp4[(h * 8 + hq) * 4 + J] = acc[J];
                if (hq == 0) mxs[h] = mx;
            }
        }
    }
    __syncthreads();

    // ---- P2b: attention epilogue. waves 0-11 = (i, pair); lane = hq|slice2(2b)|bh ----
    {
        int w = tid >> 6, lane = tid & 63;
        if (w < 12) {
            int i = w >> 2, wp = w & 3;
            int hq = lane & 7, slice2 = (lane >> 3) & 3, bh = lane >> 5;
            int b = wp * 2 + bh;
            int u = i * 8 + b;
            float aff = affw[i];
            const v4f* Wb4 = (const v4f*)WcT + (size_t)i * 3712;
            const float* fb = featf + b * 468;
            const v4f* frow = (const v4f*)fb;
            v4f Ms[NJ];
            #pragma unroll
            for (int J = 0; J < NJ; ++J)
                Ms[J] = Mp4[((2 * u) * 8 + hq) * 4 + J] + Mp4[((2 * u + 1) * 8 + hq) * 4 + J];
            float gmax = fabsf(aff) * fmaxf(mxs[2 * u], mxs[2 * u + 1]);

            v4f wW4 = ((const v4f*)wWs)[i * 8 + hq];
            v4f wH4 = ((const v4f*)wHs)[i * 8 + hq];
            int e4lo = slice2 * 10;
            int e4hi = (slice2 == 3) ? 38 : (e4lo + 10);
            for (int e4 = e4lo; e4 < e4hi; ++e4) {
                v4f s4 = frow[i * 38 + e4];
                float ores[4];
                #pragma unroll
                for (int r = 0; r < 4; ++r) {
                    float s = (r == 0) ? s4.x : (r == 1) ? s4.y : (r == 2) ? s4.z : s4.w;
                    v4f a4;
                    if (fabsf(s) * gmax <= X0f) {
                        float s2 = s * s, p = s;
                        a4 = Ms[0] * p;
                        #pragma unroll
                        for (int J = 1; J < NJ; ++J) { p *= s2; a4 += p * Ms[J]; }
                    } else {
                        a4 = (v4f)0.f;
                        for (int c = 0; c < 456; ++c) {
                            float t = tanhf(s * aff * fb[c]);
                            a4 += t * Wb4[(size_t)c * 8 + hq];
                        }
                    }
                    v4f hv = s * wW4 + a4;
                    hv = __builtin_elementwise_max(hv, (v4f)0.f);
                    v4f dv = hv * wH4;
                    float csum = dv.x + dv.y + dv.z + dv.w;
                    csum += __shfl_xor(csum, 1);
                    csum += __shfl_xor(csum, 2);
                    csum += __shfl_xor(csum, 4);
                    ores[r] = csum + s;
                }
                if (hq == 0)
                    ((v4f*)(fof + b * 468))[i * 38 + e4] = (v4f){ ores[0], ores[1], ores[2], ores[3] };
            }
        }
    }
    __syncthreads();

    // ---- P3a: classifier stage 1. 1024 tasks = (cs = t>>8, b = (t&255)&7, k4 = (t&255)>>3) ----
    {
        int cs = tid >> 8;
        int rr = tid & 255;
        int b = rr & 7, k4 = rr >> 3;
        const v4f* W14 = (const v4f*)W1T + k4;
        const v4f* fr = (const v4f*)(fof + b * 468);
        v4f a = (v4f)0.f;
        int c4lo = (cs < 2) ? cs * 29 : 58 + (cs - 2) * 28;
        int c4n  = (cs < 2) ? 29 : 28;
        for (int k = 0; k < c4n; ++k) {
            int c4 = c4lo + k;
            v4f fv = fr[c4];
            v4f w0 = W14[(c4 * 4 + 0) * 32];
            v4f w1 = W14[(c4 * 4 + 1) * 32];
            v4f w2 = W14[(c4 * 4 + 2) * 32];
            v4f w3 = W14[(c4 * 4 + 3) * 32];
            a += fv.x * w0;
            a += fv.y * w1;
            a += fv.z * w2;
            a += fv.w * w3;
        }
        clsP4[(cs * 8 + b) * 32 + k4] = a;
    }
    __syncthreads();
    if (tid < 256) {
        int b = tid >> 5, k4 = tid & 31;
        v4f v = ((const v4f*)cb1)[k4];
        #pragma unroll
        for (int cs = 0; cs < 4; ++cs) v += clsP4[(cs * 8 + b) * 32 + k4];
        ((v4f*)(featf + b * 468))[k4] = v;  // feat row reused as hs[128]
    }
    __syncthreads();
    if (tid < NB * 7) {
        int b = tid / 7, o = tid - (tid / 7) * 7;
        const v4f* hb = (const v4f*)(featf + b * 468);
        const v4f* w2 = (const v4f*)(cW2 + o * 128);
        v4f a4 = (v4f)0.f;
        #pragma unroll 8
        for (int k4 = 0; k4 < 32; ++k4) a4 += hb[k4] * w2[k4];
        out[(size_t)(b0 + b) * 7 + o] = cb2[o] + a4.x + a4.y + a4.z + a4.w;
    }
}

// ---------------- host: Chebyshev fit of tanh on [-1.1,1.1], odd monomials ----------------
static void make_poly(float* cf) {
    const double a = 1.1;
    const int NQ = 128;
    const double PI = 3.14159265358979323846;
    double b[DEG + 1];
    for (int k = 0; k <= DEG; ++k) b[k] = 0.0;
    for (int m = 0; m < NQ; ++m) {
        double th = PI * (m + 0.5) / NQ;
        double f = tanh(a * cos(th));
        for (int k = 1; k <= DEG; k += 2)
            b[k] += (2.0 / NQ) * f * cos(k * th);
    }
    double Tp[DEG + 1], Tc[DEG + 1], Tn[DEG + 1], mono[DEG + 1];
    for (int j = 0; j <= DEG; ++j) { Tp[j] = 0; Tc[j] = 0; mono[j] = 0; }
    Tp[0] = 1.0;
    Tc[1] = 1.0;
    for (int j = 0; j <= DEG; ++j) mono[j] += b[1] * Tc[j];
    for (int k = 2; k <= DEG; ++k) {
        for (int j = 0; j <= DEG; ++j) Tn[j] = -Tp[j];
        for (int j = 1; j <= DEG; ++j) Tn[j] += 2.0 * Tc[j - 1];
        for (int j = 0; j <= DEG; ++j) { Tp[j] = Tc[j]; Tc[j] = Tn[j]; }
        if (k & 1) for (int j = 0; j <= DEG; ++j) mono[j] += b[k] * Tc[j];
    }
    for (int J = 0; J < NJ; ++J) {
        int j = 2 * J + 1;
        cf[J] = (float)(mono[j] / pow(a, (double)j));
    }
}

extern "C" void kernel_launch(void* const* d_in, const int* in_sizes, int n_in,
                              void* d_out, int out_size, void* d_ws, size_t ws_size,
                              hipStream_t stream) {
    (void)in_sizes; (void)n_in; (void)out_size; (void)ws_size;
    const float* x0    = (const float*)d_in[0];
    const float* x1    = (const float*)d_in[1];
    const float* x2    = (const float*)d_in[2];
    const float* eW0   = (const float*)d_in[3];
    const float* eb0   = (const float*)d_in[4];
    const float* eW1   = (const float*)d_in[5];
    const float* eb1   = (const float*)d_in[6];
    const float* eW2   = (const float*)d_in[7];
    const float* eb2   = (const float*)d_in[8];
    const float* affw  = (const float*)d_in[9];
    const float* Ww    = (const float*)d_in[10];
    const float* Wc    = (const float*)d_in[11];
    const float* Wh    = (const float*)d_in[12];
    const float* cW1   = (const float*)d_in[13];
    const float* cb1   = (const float*)d_in[14];
    const float* cW2   = (const float*)d_in[15];
    const float* cb2   = (const float*)d_in[16];

    float* ws    = (float*)d_ws;
    float* wsWcT = ws;                 // 3*464*32  = 44544
    float* wsW1T = ws + 44544;         // 456*128   = 58368
    float* wsWt0 = ws + 102912;        // 304*152   = 46208
    float* wsWt1 = ws + 149120;        // 76*152    = 11552
    float* wsWt2 = ws + 160672;        // 36*152    = 5472

    Poly pc;
    make_poly(pc.c);

    k_repack<<<dim3(96), dim3(256), 0, stream>>>(Wc, cW1, eW0, eW1, eW2,
                                                 wsWcT, wsW1T, wsWt0, wsWt1, wsWt2);
    k_fused<<<dim3(256), dim3(NT), 0, stream>>>(x0, x1, x2, eb0, eb1, eb2,
                                                wsWt0, wsWt1, wsWt2, wsWcT,
                                                affw, Ww, Wh, wsW1T, cb1, cW2, cb2,
                                                (float*)d_out, pc);
}